// Round 9
// baseline (159.897 us; speedup 1.0000x reference)
//
#include <hip/hip_runtime.h>
#include <hip/hip_bf16.h>
#include <cfloat>

#define C_NUM 80
#define REG_MAXP1 17
#define NS 33          // register slots in fallback assign kernel: covers A <= 8448
#define MAXA 8448      // LDS mask capacity in raster kernels
#define FG_STRIDE 512  // per-image fg-list capacity (>= G*k = 260)

// ---------------- analytic candidate-window helpers (A == 8400 geometry) ----------------
// level0 80x80 @ (ix+0.5)*8  base 0 | level1 40x40 @ (ix+0.5)*16 base 6400 | level2 20x20 @ (ix+0.5)*32 base 8000
// Top-13 nearest anchors lie within: 6x6 window (grid0) + 4x4 (grid1) + 4x4 (grid2) = 68 candidates.
__device__ inline void cand_for_slot(int sc, float cx, float cy, float& v, int& idx)
{
    v = FLT_MAX; idx = 0x7fffffff;
    int loc, w, n, strd, base;
    if (sc < 36)      { loc = sc;      w = 6; n = 80; strd = 8;  base = 0; }
    else if (sc < 52) { loc = sc - 36; w = 4; n = 40; strd = 16; base = 6400; }
    else if (sc < 68) { loc = sc - 52; w = 4; n = 20; strd = 32; base = 8000; }
    else return;
    float inv = 1.0f / (float)strd;                     // power-of-2: exact
    int ix0 = (int)floorf(cx * inv - 0.5f) - (w / 2 - 1);
    int iy0 = (int)floorf(cy * inv - 0.5f) - (w / 2 - 1);
    int ix = ix0 + loc % w, iy = iy0 + loc / w;
    if (ix < 0 || ix >= n || iy < 0 || iy >= n) return;
    float ax = ((float)ix + 0.5f) * (float)strd;        // exact fp32, matches _make_anchors
    float ay = ((float)iy + 0.5f) * (float)strd;
    float dx = ax - cx, dy = ay - cy;
    v = dx * dx + dy * dy;
    idx = base + iy * n + ix;
}

// ---------------- K1 (fast, fused): per-image assign (wave per gt) + raster in LDS ----------------
__global__ __launch_bounds__(1024) void assignraster_kernel(const float* __restrict__ gt_boxes,
                              unsigned int* __restrict__ mask,
                              int* __restrict__ fglist,
                              int* __restrict__ npos,
                              float* __restrict__ acc,
                              int A, int G, int k)
{
    __shared__ unsigned int lmask[8400];
    __shared__ int s_cnt;
    int b = blockIdx.x, t = threadIdx.x;
    int wv = t >> 6, lane = t & 63;

    for (int i = t; i < A; i += 1024) lmask[i] = 0u;
    if (t == 0) s_cnt = 0;
    if (t < 3) acc[b * 3 + t] = 0.f;
    __syncthreads();

    // ---- assign phase: each wave owns gts g = wv, wv+16, ... (no barriers inside) ----
    for (int g = wv; g < G; g += 16) {
        const float* box = gt_boxes + (size_t)(b * G + g) * 4;
        float x0 = box[0], y0 = box[1], x1 = box[2], y1 = box[3];
        float cx = (x0 + x1) * 0.5f, cy = (y0 + y1) * 0.5f;

        float v0, v1; int i0, i1;
        cand_for_slot(lane,      cx, cy, v0, i0);
        cand_for_slot(lane + 64, cx, cy, v1, i1);

        int my_sel = 0x7fffffff;
        for (int it = 0; it < k; ++it) {
            float lb; int li; bool s0;
            if (v0 < v1 || (v0 == v1 && i0 < i1)) { lb = v0; li = i0; s0 = true; }
            else                                   { lb = v1; li = i1; s0 = false; }
            float rb = lb; int ri = li;
            for (int off = 32; off; off >>= 1) {   // wave argmin, tie -> lower index (lax.top_k order)
                float ov = __shfl_down(rb, off);
                int   oi = __shfl_down(ri, off);
                if (ov < rb || (ov == rb && oi < ri)) { rb = ov; ri = oi; }
            }
            int win = __shfl(ri, 0);
            if (lane == it) my_sel = win;
            if (li == win) {                        // unique indices -> exactly the owner invalidates
                if (s0) { v0 = FLT_MAX; i0 = 0x7fffffff; }
                else    { v1 = FLT_MAX; i1 = 0x7fffffff; }
            }
        }

        bool inside = false;
        if (lane < k && my_sel < 0x7fffffff) {
            int idx = my_sel, n, strd, base;
            if (idx < 6400)      { n = 80; strd = 8;  base = 0; }
            else if (idx < 8000) { n = 40; strd = 16; base = 6400; }
            else                 { n = 20; strd = 32; base = 8000; }
            int loc = idx - base;
            float ax = ((float)(loc % n) + 0.5f) * (float)strd;
            float ay = ((float)(loc / n) + 0.5f) * (float)strd;
            inside = (ax >= x0) && (ax <= x1) && (ay >= y0) && (ay <= y1);
        }
        unsigned long long ball = __ballot(inside);
        if (lane < k && my_sel < 0x7fffffff) {
            bool asg = ball ? inside : (lane < 3);
            if (asg) atomicOr(&lmask[my_sel], 1u << g);
        }
    }
    __syncthreads();

    // ---- raster phase: ballot-compacted fg list, one LDS atomic per wave-iteration ----
    for (int i = t; i < A; i += 1024) {
        unsigned int m = lmask[i];
        mask[(size_t)b * A + i] = m;
        bool fg = (m != 0u);
        unsigned long long bal = __ballot(fg);
        int cnt = __popcll(bal);
        int base = 0;
        if (lane == 0 && cnt) base = atomicAdd(&s_cnt, cnt);
        base = __shfl(base, 0);
        if (fg) {
            int pre = __popcll(bal & ((1ull << lane) - 1ull));
            fglist[b * FG_STRIDE + base + pre] = i | ((31 - __clz(m)) << 16);
        }
    }
    __syncthreads();
    if (t == 0) npos[b] = s_cnt;
}

// ---------------- K1 (fallback, A != 8400): register-scan top-k -> sel ----------------
__global__ __launch_bounds__(256) void assign_kernel(const float* __restrict__ gt_boxes,
                              const float* __restrict__ anchor_points,
                              int* __restrict__ sel,
                              int B, int A, int G, int k)
{
    __shared__ float s_val[4];
    __shared__ int   s_idx[4];
    __shared__ int   s_sel;
    __shared__ int   s_topk[16];
    __shared__ int   s_anyin;

    int bg = blockIdx.x;
    int b = bg / G, g = bg % G;
    const float* box = gt_boxes + (size_t)(b * G + g) * 4;
    float x0 = box[0], y0 = box[1], x1 = box[2], y1 = box[3];
    float cx = (x0 + x1) * 0.5f, cy = (y0 + y1) * 0.5f;

    int t = threadIdx.x;
    float dv[NS];
#pragma unroll
    for (int s = 0; s < NS; ++s) {
        int i = t + s * 256;
        float d = FLT_MAX;
        if (i < A) {
            float dx = anchor_points[2 * i] - cx;
            float dy = anchor_points[2 * i + 1] - cy;
            d = dx * dx + dy * dy;
        }
        dv[s] = d;
    }

    int wid = t >> 6, lane = t & 63;
    for (int it = 0; it < k; ++it) {
        float best = FLT_MAX; int bi = 0x7fffffff;
#pragma unroll
        for (int s = 0; s < NS; ++s) {
            if (dv[s] < best) { best = dv[s]; bi = t + s * 256; }
        }
        for (int off = 32; off; off >>= 1) {
            float ov = __shfl_down(best, off);
            int   oi = __shfl_down(bi, off);
            if (ov < best || (ov == best && oi < bi)) { best = ov; bi = oi; }
        }
        if (lane == 0) { s_val[wid] = best; s_idx[wid] = bi; }
        __syncthreads();
        if (t == 0) {
            float bv = s_val[0]; int bix = s_idx[0];
#pragma unroll
            for (int w = 1; w < 4; ++w) {
                if (s_val[w] < bv || (s_val[w] == bv && s_idx[w] < bix)) { bv = s_val[w]; bix = s_idx[w]; }
            }
            s_sel = bix;
            s_topk[it] = bix;
        }
        __syncthreads();
        int selx = s_sel;
        if ((selx & 255) == t) {
            int slot = selx >> 8;
#pragma unroll
            for (int s = 0; s < NS; ++s) if (s == slot) dv[s] = FLT_MAX;
        }
    }

    if (t == 0) s_anyin = 0;
    __syncthreads();
    bool inside = false; int aidx = -1;
    if (t < k) {
        aidx = s_topk[t];
        float ax = anchor_points[2 * aidx], ay = anchor_points[2 * aidx + 1];
        inside = (ax >= x0) && (ax <= x1) && (ay >= y0) && (ay <= y1);
        if (inside) atomicOr(&s_anyin, 1);
    }
    __syncthreads();
    if (t < k) {
        bool asg = s_anyin ? inside : (t < 3);
        sel[(size_t)bg * 16 + t] = asg ? aidx : -1;
    }
}

// ---------------- K2 (fallback): rasterize per image from sel ----------------
__global__ __launch_bounds__(256) void raster_kernel(const int* __restrict__ sel,
                              unsigned int* __restrict__ mask,
                              int* __restrict__ fglist,
                              int* __restrict__ npos,
                              float* __restrict__ acc,
                              int A, int G, int k)
{
    __shared__ unsigned int lmask[MAXA];
    __shared__ int s_cnt;
    int b = blockIdx.x, t = threadIdx.x;

    for (int i = t; i < A; i += 256) lmask[i] = 0u;
    if (t == 0) s_cnt = 0;
    if (t < 3) acc[b * 3 + t] = 0.f;
    __syncthreads();

    for (int i = t; i < G * 16; i += 256) {
        int slot = i & 15;
        if (slot < k) {
            int a = sel[(size_t)(b * G) * 16 + i];
            if (a >= 0) atomicOr(&lmask[a], 1u << (i >> 4));
        }
    }
    __syncthreads();

    for (int i = t; i < A; i += 256) {
        unsigned int m = lmask[i];
        mask[(size_t)b * A + i] = m;
        if (m) {
            int lg = 31 - __clz(m);
            int p = atomicAdd(&s_cnt, 1);
            fglist[b * FG_STRIDE + p] = i | (lg << 16);
        }
    }
    __syncthreads();
    if (t == 0) npos[b] = s_cnt;
}

// ---------------- K3: fused streaming BCE + low-VGPR box phase ----------------
__global__ __launch_bounds__(256) void clsbox_kernel(const float4* __restrict__ cls,
                           const float* __restrict__ reg,
                           const float* __restrict__ gt_boxes,
                           const float* __restrict__ ap,
                           const float* __restrict__ st,
                           const unsigned int* __restrict__ mask,
                           const int* __restrict__ gt_labels,
                           const int* __restrict__ fglist,
                           const int* __restrict__ npos,
                           float* __restrict__ acc, int A, int G)
{
    const int CQ = C_NUM / 4;
    int b = blockIdx.y;
    int nq = A * CQ;
    const float4* base = cls + (size_t)b * nq;
    const unsigned int* mrow = mask + (size_t)b * A;
    const int* lab = gt_labels + (size_t)b * G;

    float pos = 0.f, neg = 0.f;
    for (int q = blockIdx.x * 256 + threadIdx.x; q < nq; q += gridDim.x * 256) {
        float4 v = base[q];
        unsigned int m = mrow[q / CQ];
        float p0 = fminf(fmaxf(v.x, 1e-7f), 1.0f - 1e-7f);
        float p1 = fminf(fmaxf(v.y, 1e-7f), 1.0f - 1e-7f);
        float p2 = fminf(fmaxf(v.z, 1e-7f), 1.0f - 1e-7f);
        float p3 = fminf(fmaxf(v.w, 1e-7f), 1.0f - 1e-7f);
        if (m) {
            int c0 = (q % CQ) * 4;
            unsigned int tm = 0, mm = m;
            while (mm) {
                int g = __ffs(mm) - 1;
                mm &= mm - 1;
                unsigned int d = (unsigned int)(lab[g] - c0);
                if (d < 4u) tm |= 1u << d;
            }
            pos -= __logf((tm & 1u) ? p0 : 1.0f - p0);
            pos -= __logf((tm & 2u) ? p1 : 1.0f - p1);
            pos -= __logf((tm & 4u) ? p2 : 1.0f - p2);
            pos -= __logf((tm & 8u) ? p3 : 1.0f - p3);
        } else {
            neg -= __logf(1.0f - p0) + __logf(1.0f - p1) + __logf(1.0f - p2) + __logf(1.0f - p3);
        }
    }

    // ---- box phase: compacted fg entries, per-side rr[17] (no spill) ----
    float bx = 0.f;
    int e = blockIdx.x * 256 + threadIdx.x;
    if (e < npos[b]) {
        int ent = fglist[b * FG_STRIDE + e];
        int a = ent & 0xffff;
        int lg = ent >> 16;
        const float* tb = gt_boxes + (size_t)(b * G + lg) * 4;
        const float* r = reg + ((size_t)b * A + a) * (4 * REG_MAXP1);
        float s = st[a];
        float axp = ap[2 * a], ayp = ap[2 * a + 1];
#pragma unroll
        for (int j = 0; j < 4; ++j) {
            const float* rj = r + j * REG_MAXP1;
            float rr[REG_MAXP1];
#pragma unroll
            for (int i = 0; i < REG_MAXP1; ++i) rr[i] = rj[i];
            float mx = rr[0];
#pragma unroll
            for (int i = 1; i < REG_MAXP1; ++i) mx = fmaxf(mx, rr[i]);
            float sum = 0.f, dot = 0.f;
#pragma unroll
            for (int i = 0; i < REG_MAXP1; ++i) {
                float ev = __expf(rr[i] - mx);
                sum += ev; dot += ev * (float)i;
            }
            float dist = dot / sum;
            float pbj = (j < 2) ? ((j == 0 ? axp : ayp) - dist * s)
                                : ((j == 2 ? axp : ayp) + dist * s);
            float df = pbj - tb[j];
            float ad = fabsf(df);
            bx += (ad < 1.0f) ? 0.5f * df * df : ad - 0.5f;
        }
    }

    for (int off = 32; off; off >>= 1) {
        pos += __shfl_down(pos, off);
        neg += __shfl_down(neg, off);
        bx  += __shfl_down(bx, off);
    }
    __shared__ float sp[4], sn[4], sb[4];
    int wid = threadIdx.x >> 6, lane = threadIdx.x & 63;
    if (lane == 0) { sp[wid] = pos; sn[wid] = neg; sb[wid] = bx; }
    __syncthreads();
    if (threadIdx.x == 0) {
        float P = sp[0] + sp[1] + sp[2] + sp[3];
        float N = sn[0] + sn[1] + sn[2] + sn[3];
        float X = sb[0] + sb[1] + sb[2] + sb[3];
        if (P != 0.f) atomicAdd(&acc[b * 3 + 0], P);
        if (N != 0.f) atomicAdd(&acc[b * 3 + 1], N);
        if (X != 0.f) atomicAdd(&acc[b * 3 + 2], X);
    }
}

// ---------------- K4: final scalar ----------------
__global__ void final_kernel(const float* __restrict__ acc,
                             const int* __restrict__ npos,
                             float* __restrict__ out, int B, int A)
{
    if (threadIdx.x == 0 && blockIdx.x == 0) {
        float cls_sum = 0.f, box_sum = 0.f;
        for (int b = 0; b < B; ++b) {
            float np = (float)npos[b];
            float neg = acc[b * 3 + 1] / fmaxf(((float)A - np) * (float)C_NUM, 1.0f);
            float pos = 0.f, box = 0.f;
            if (np > 0.f) {
                float pw = fminf((float)A / fmaxf(np, 1.0f), 50.0f);
                pos = acc[b * 3 + 0] / fmaxf(np * (float)C_NUM, 1.0f) * pw;
                box = acc[b * 3 + 2] / fmaxf(np * 4.0f, 1.0f);
            }
            cls_sum += pos + neg;
            box_sum += box;
        }
        out[0] = cls_sum / (float)B * 1.0f + box_sum / (float)B * 2.5f;
    }
}

extern "C" void kernel_launch(void* const* d_in, const int* in_sizes, int n_in,
                              void* d_out, int out_size, void* d_ws, size_t ws_size,
                              hipStream_t stream)
{
    const float* cls   = (const float*)d_in[0];
    const float* reg   = (const float*)d_in[1];
    const float* gtb   = (const float*)d_in[2];
    const float* ap    = (const float*)d_in[3];
    const float* st    = (const float*)d_in[4];
    const int*   glab  = (const int*)d_in[5];

    int A = in_sizes[3] / 2;
    int B = in_sizes[0] / (A * C_NUM);
    int G = in_sizes[5] / B;
    int k = A / (G > 1 ? G : 1); if (k > 13) k = 13; if (k < 3) k = 3;

    // ws layout
    unsigned int* mask = (unsigned int*)d_ws;                       // B*A
    float* acc   = (float*)(mask + (size_t)B * A);                  // 3*B
    int*   npos  = (int*)(acc + 3 * B);                             // B
    int*   sel   = npos + B;                                        // B*G*16 (fallback only)
    int*   fgl   = sel + (size_t)B * G * 16;                        // B*FG_STRIDE

    if (A == 8400 && G <= 32) {
        assignraster_kernel<<<B, 1024, 0, stream>>>(gtb, mask, fgl, npos, acc, A, G, k);
    } else {
        assign_kernel<<<B * G, 256, 0, stream>>>(gtb, ap, sel, B, A, G, k);
        raster_kernel<<<B, 256, 0, stream>>>(sel, mask, fgl, npos, acc, A, G, k);
    }

    dim3 g3(128, B);
    clsbox_kernel<<<g3, 256, 0, stream>>>((const float4*)cls, reg, gtb, ap, st,
                                          mask, glab, fgl, npos, acc, A, G);

    final_kernel<<<1, 64, 0, stream>>>(acc, npos, (float*)d_out, B, A);
}

// Round 10
// 154.788 us; speedup vs baseline: 1.0330x; 1.0330x over previous
//
#include <hip/hip_runtime.h>
#include <hip/hip_bf16.h>
#include <cfloat>

#define C_NUM 80
#define REG_MAXP1 17
#define NS 33          // register slots in fallback assign kernel: covers A <= 8448
#define MAXA 8448      // LDS mask capacity in raster kernels
#define FG_STRIDE 512  // per-image fg-list capacity (>= G*k = 260)

// ---------------- analytic candidate-window helpers (A == 8400 geometry) ----------------
// level0 80x80 @ (ix+0.5)*8  base 0 | level1 40x40 @ (ix+0.5)*16 base 6400 | level2 20x20 @ (ix+0.5)*32 base 8000
// Top-13 nearest anchors lie within: 6x6 window (grid0) + 4x4 (grid1) + 4x4 (grid2) = 68 candidates.
__device__ inline void cand_for_slot(int sc, float cx, float cy, float& v, int& idx)
{
    v = FLT_MAX; idx = 0x7fffffff;
    int loc, w, n, strd, base;
    if (sc < 36)      { loc = sc;      w = 6; n = 80; strd = 8;  base = 0; }
    else if (sc < 52) { loc = sc - 36; w = 4; n = 40; strd = 16; base = 6400; }
    else if (sc < 68) { loc = sc - 52; w = 4; n = 20; strd = 32; base = 8000; }
    else return;
    float inv = 1.0f / (float)strd;                     // power-of-2: exact
    int ix0 = (int)floorf(cx * inv - 0.5f) - (w / 2 - 1);
    int iy0 = (int)floorf(cy * inv - 0.5f) - (w / 2 - 1);
    int ix = ix0 + loc % w, iy = iy0 + loc / w;
    if (ix < 0 || ix >= n || iy < 0 || iy >= n) return;
    float ax = ((float)ix + 0.5f) * (float)strd;        // exact fp32, matches _make_anchors
    float ay = ((float)iy + 0.5f) * (float)strd;
    float dx = ax - cx, dy = ay - cy;
    v = dx * dx + dy * dy;
    idx = base + iy * n + ix;
}

// ---------------- K1 (fast, fused): per-image assign (wave per gt) + raster in LDS ----------------
__global__ __launch_bounds__(1024) void assignraster_kernel(const float* __restrict__ gt_boxes,
                              unsigned int* __restrict__ mask,
                              int* __restrict__ fglist,
                              int* __restrict__ npos,
                              float* __restrict__ acc,
                              int A, int G, int k)
{
    __shared__ unsigned int lmask[8400];
    __shared__ int s_cnt;
    int b = blockIdx.x, t = threadIdx.x;
    int wv = t >> 6, lane = t & 63;

    for (int i = t; i < A; i += 1024) lmask[i] = 0u;
    if (t == 0) s_cnt = 0;
    if (t < 3) acc[b * 3 + t] = 0.f;
    __syncthreads();

    // ---- assign phase: each wave owns gts g = wv, wv+16, ... (no barriers inside) ----
    for (int g = wv; g < G; g += 16) {
        const float* box = gt_boxes + (size_t)(b * G + g) * 4;
        float x0 = box[0], y0 = box[1], x1 = box[2], y1 = box[3];
        float cx = (x0 + x1) * 0.5f, cy = (y0 + y1) * 0.5f;

        float v0, v1; int i0, i1;
        cand_for_slot(lane,      cx, cy, v0, i0);
        cand_for_slot(lane + 64, cx, cy, v1, i1);

        int my_sel = 0x7fffffff;
        for (int it = 0; it < k; ++it) {
            float lb; int li; bool s0;
            if (v0 < v1 || (v0 == v1 && i0 < i1)) { lb = v0; li = i0; s0 = true; }
            else                                   { lb = v1; li = i1; s0 = false; }
            float rb = lb; int ri = li;
            for (int off = 32; off; off >>= 1) {   // wave argmin, tie -> lower index (lax.top_k order)
                float ov = __shfl_down(rb, off);
                int   oi = __shfl_down(ri, off);
                if (ov < rb || (ov == rb && oi < ri)) { rb = ov; ri = oi; }
            }
            int win = __shfl(ri, 0);
            if (lane == it) my_sel = win;
            if (li == win) {                        // unique indices -> exactly the owner invalidates
                if (s0) { v0 = FLT_MAX; i0 = 0x7fffffff; }
                else    { v1 = FLT_MAX; i1 = 0x7fffffff; }
            }
        }

        bool inside = false;
        if (lane < k && my_sel < 0x7fffffff) {
            int idx = my_sel, n, strd, base;
            if (idx < 6400)      { n = 80; strd = 8;  base = 0; }
            else if (idx < 8000) { n = 40; strd = 16; base = 6400; }
            else                 { n = 20; strd = 32; base = 8000; }
            int loc = idx - base;
            float ax = ((float)(loc % n) + 0.5f) * (float)strd;
            float ay = ((float)(loc / n) + 0.5f) * (float)strd;
            inside = (ax >= x0) && (ax <= x1) && (ay >= y0) && (ay <= y1);
        }
        unsigned long long ball = __ballot(inside);
        if (lane < k && my_sel < 0x7fffffff) {
            bool asg = ball ? inside : (lane < 3);
            if (asg) atomicOr(&lmask[my_sel], 1u << g);
        }
    }
    __syncthreads();

    // ---- raster phase: ballot-compacted fg list, one LDS atomic per wave-iteration ----
    for (int i = t; i < A; i += 1024) {
        unsigned int m = lmask[i];
        mask[(size_t)b * A + i] = m;
        bool fg = (m != 0u);
        unsigned long long bal = __ballot(fg);
        int cnt = __popcll(bal);
        int base = 0;
        if (lane == 0 && cnt) base = atomicAdd(&s_cnt, cnt);
        base = __shfl(base, 0);
        if (fg) {
            int pre = __popcll(bal & ((1ull << lane) - 1ull));
            fglist[b * FG_STRIDE + base + pre] = i | ((31 - __clz(m)) << 16);
        }
    }
    __syncthreads();
    if (t == 0) npos[b] = s_cnt;
}

// ---------------- K1 (fallback, A != 8400): register-scan top-k -> sel ----------------
__global__ __launch_bounds__(256) void assign_kernel(const float* __restrict__ gt_boxes,
                              const float* __restrict__ anchor_points,
                              int* __restrict__ sel,
                              int B, int A, int G, int k)
{
    __shared__ float s_val[4];
    __shared__ int   s_idx[4];
    __shared__ int   s_sel;
    __shared__ int   s_topk[16];
    __shared__ int   s_anyin;

    int bg = blockIdx.x;
    int b = bg / G, g = bg % G;
    const float* box = gt_boxes + (size_t)(b * G + g) * 4;
    float x0 = box[0], y0 = box[1], x1 = box[2], y1 = box[3];
    float cx = (x0 + x1) * 0.5f, cy = (y0 + y1) * 0.5f;

    int t = threadIdx.x;
    float dv[NS];
#pragma unroll
    for (int s = 0; s < NS; ++s) {
        int i = t + s * 256;
        float d = FLT_MAX;
        if (i < A) {
            float dx = anchor_points[2 * i] - cx;
            float dy = anchor_points[2 * i + 1] - cy;
            d = dx * dx + dy * dy;
        }
        dv[s] = d;
    }

    int wid = t >> 6, lane = t & 63;
    for (int it = 0; it < k; ++it) {
        float best = FLT_MAX; int bi = 0x7fffffff;
#pragma unroll
        for (int s = 0; s < NS; ++s) {
            if (dv[s] < best) { best = dv[s]; bi = t + s * 256; }
        }
        for (int off = 32; off; off >>= 1) {
            float ov = __shfl_down(best, off);
            int   oi = __shfl_down(bi, off);
            if (ov < best || (ov == best && oi < bi)) { best = ov; bi = oi; }
        }
        if (lane == 0) { s_val[wid] = best; s_idx[wid] = bi; }
        __syncthreads();
        if (t == 0) {
            float bv = s_val[0]; int bix = s_idx[0];
#pragma unroll
            for (int w = 1; w < 4; ++w) {
                if (s_val[w] < bv || (s_val[w] == bv && s_idx[w] < bix)) { bv = s_val[w]; bix = s_idx[w]; }
            }
            s_sel = bix;
            s_topk[it] = bix;
        }
        __syncthreads();
        int selx = s_sel;
        if ((selx & 255) == t) {
            int slot = selx >> 8;
#pragma unroll
            for (int s = 0; s < NS; ++s) if (s == slot) dv[s] = FLT_MAX;
        }
    }

    if (t == 0) s_anyin = 0;
    __syncthreads();
    bool inside = false; int aidx = -1;
    if (t < k) {
        aidx = s_topk[t];
        float ax = anchor_points[2 * aidx], ay = anchor_points[2 * aidx + 1];
        inside = (ax >= x0) && (ax <= x1) && (ay >= y0) && (ay <= y1);
        if (inside) atomicOr(&s_anyin, 1);
    }
    __syncthreads();
    if (t < k) {
        bool asg = s_anyin ? inside : (t < 3);
        sel[(size_t)bg * 16 + t] = asg ? aidx : -1;
    }
}

// ---------------- K2 (fallback): rasterize per image from sel ----------------
__global__ __launch_bounds__(256) void raster_kernel(const int* __restrict__ sel,
                              unsigned int* __restrict__ mask,
                              int* __restrict__ fglist,
                              int* __restrict__ npos,
                              float* __restrict__ acc,
                              int A, int G, int k)
{
    __shared__ unsigned int lmask[MAXA];
    __shared__ int s_cnt;
    int b = blockIdx.x, t = threadIdx.x;

    for (int i = t; i < A; i += 256) lmask[i] = 0u;
    if (t == 0) s_cnt = 0;
    if (t < 3) acc[b * 3 + t] = 0.f;
    __syncthreads();

    for (int i = t; i < G * 16; i += 256) {
        int slot = i & 15;
        if (slot < k) {
            int a = sel[(size_t)(b * G) * 16 + i];
            if (a >= 0) atomicOr(&lmask[a], 1u << (i >> 4));
        }
    }
    __syncthreads();

    for (int i = t; i < A; i += 256) {
        unsigned int m = lmask[i];
        mask[(size_t)b * A + i] = m;
        if (m) {
            int lg = 31 - __clz(m);
            int p = atomicAdd(&s_cnt, 1);
            fglist[b * FG_STRIDE + p] = i | (lg << 16);
        }
    }
    __syncthreads();
    if (t == 0) npos[b] = s_cnt;
}

// ---------------- BCE helper ----------------
__device__ inline void bce4(float4 v, unsigned int m, const int* __restrict__ lab,
                            int c0, float& pos, float& neg)
{
    float p0 = fminf(fmaxf(v.x, 1e-7f), 1.0f - 1e-7f);
    float p1 = fminf(fmaxf(v.y, 1e-7f), 1.0f - 1e-7f);
    float p2 = fminf(fmaxf(v.z, 1e-7f), 1.0f - 1e-7f);
    float p3 = fminf(fmaxf(v.w, 1e-7f), 1.0f - 1e-7f);
    if (m) {
        unsigned int tm = 0, mm = m;
        while (mm) {
            int g = __ffs(mm) - 1;
            mm &= mm - 1;
            unsigned int d = (unsigned int)(lab[g] - c0);
            if (d < 4u) tm |= 1u << d;
        }
        pos -= __logf((tm & 1u) ? p0 : 1.0f - p0);
        pos -= __logf((tm & 2u) ? p1 : 1.0f - p1);
        pos -= __logf((tm & 4u) ? p2 : 1.0f - p2);
        pos -= __logf((tm & 8u) ? p3 : 1.0f - p3);
    } else {
        neg -= __logf(1.0f - p0) + __logf(1.0f - p1) + __logf(1.0f - p2) + __logf(1.0f - p3);
    }
}

// ---------------- K3: streaming BCE, 2-way unrolled grid-stride ----------------
__global__ __launch_bounds__(256) void cls_kernel(const float4* __restrict__ cls,
                           const unsigned int* __restrict__ mask,
                           const int* __restrict__ gt_labels,
                           float* __restrict__ acc, int A, int G)
{
    const int CQ = C_NUM / 4;
    int b = blockIdx.y;
    int nq = A * CQ;
    const float4* base = cls + (size_t)b * nq;
    const unsigned int* mrow = mask + (size_t)b * A;
    const int* lab = gt_labels + (size_t)b * G;
    int stride = gridDim.x * 256;

    float pos = 0.f, neg = 0.f;
    for (int q0 = blockIdx.x * 256 + threadIdx.x; q0 < nq; q0 += 2 * stride) {
        int q1 = q0 + stride;
        bool h1 = q1 < nq;
        float4 va = base[q0];
        unsigned int ma = mrow[q0 / CQ];
        float4 vb; unsigned int mb = 0;
        if (h1) { vb = base[q1]; mb = mrow[q1 / CQ]; }
        bce4(va, ma, lab, (q0 % CQ) * 4, pos, neg);
        if (h1) bce4(vb, mb, lab, (q1 % CQ) * 4, pos, neg);
    }

    for (int off = 32; off; off >>= 1) {
        pos += __shfl_down(pos, off);
        neg += __shfl_down(neg, off);
    }
    __shared__ float sp[4], sn[4];
    int wid = threadIdx.x >> 6, lane = threadIdx.x & 63;
    if (lane == 0) { sp[wid] = pos; sn[wid] = neg; }
    __syncthreads();
    if (threadIdx.x == 0) {
        float P = sp[0] + sp[1] + sp[2] + sp[3];
        float N = sn[0] + sn[1] + sn[2] + sn[3];
        if (P != 0.f) atomicAdd(&acc[b * 3 + 0], P);
        if (N != 0.f) atomicAdd(&acc[b * 3 + 1], N);
    }
}

// ---------------- K4: box loss, (entry, side) decomposition -> 4x shorter latency chain ----------------
__global__ __launch_bounds__(256) void boxfg_kernel(const float* __restrict__ reg,
                           const float* __restrict__ gt_boxes,
                           const float* __restrict__ ap,
                           const float* __restrict__ st,
                           const int* __restrict__ fglist,
                           const int* __restrict__ npos,
                           float* __restrict__ acc, int A, int G)
{
    int b = blockIdx.y;
    int idx = blockIdx.x * 256 + threadIdx.x;
    int e = idx >> 2, j = idx & 3;          // entry, box side
    float bx = 0.f;
    if (e < npos[b]) {
        int ent = fglist[b * FG_STRIDE + e];
        int a = ent & 0xffff;
        int lg = ent >> 16;
        float tbj = gt_boxes[(size_t)(b * G + lg) * 4 + j];
        const float* rj = reg + ((size_t)b * A + a) * (4 * REG_MAXP1) + j * REG_MAXP1;
        float rr[REG_MAXP1];
#pragma unroll
        for (int i = 0; i < REG_MAXP1; ++i) rr[i] = rj[i];
        float mx = rr[0];
#pragma unroll
        for (int i = 1; i < REG_MAXP1; ++i) mx = fmaxf(mx, rr[i]);
        float sum = 0.f, dot = 0.f;
#pragma unroll
        for (int i = 0; i < REG_MAXP1; ++i) {
            float ev = __expf(rr[i] - mx);
            sum += ev; dot += ev * (float)i;
        }
        float dist = dot / sum;
        float s = st[a];
        float ac = ap[2 * a + (j & 1)];     // j even -> x, j odd -> y
        float pbj = (j < 2) ? (ac - dist * s) : (ac + dist * s);
        float df = pbj - tbj;
        float ad = fabsf(df);
        bx = (ad < 1.0f) ? 0.5f * df * df : ad - 0.5f;
    }
    for (int off = 32; off; off >>= 1) bx += __shfl_down(bx, off);
    __shared__ float sb[4];
    int wid = threadIdx.x >> 6, lane = threadIdx.x & 63;
    if (lane == 0) sb[wid] = bx;
    __syncthreads();
    if (threadIdx.x == 0) {
        float X = sb[0] + sb[1] + sb[2] + sb[3];
        if (X != 0.f) atomicAdd(&acc[b * 3 + 2], X);
    }
}

// ---------------- K5: final scalar ----------------
__global__ void final_kernel(const float* __restrict__ acc,
                             const int* __restrict__ npos,
                             float* __restrict__ out, int B, int A)
{
    if (threadIdx.x == 0 && blockIdx.x == 0) {
        float cls_sum = 0.f, box_sum = 0.f;
        for (int b = 0; b < B; ++b) {
            float np = (float)npos[b];
            float neg = acc[b * 3 + 1] / fmaxf(((float)A - np) * (float)C_NUM, 1.0f);
            float pos = 0.f, box = 0.f;
            if (np > 0.f) {
                float pw = fminf((float)A / fmaxf(np, 1.0f), 50.0f);
                pos = acc[b * 3 + 0] / fmaxf(np * (float)C_NUM, 1.0f) * pw;
                box = acc[b * 3 + 2] / fmaxf(np * 4.0f, 1.0f);
            }
            cls_sum += pos + neg;
            box_sum += box;
        }
        out[0] = cls_sum / (float)B * 1.0f + box_sum / (float)B * 2.5f;
    }
}

extern "C" void kernel_launch(void* const* d_in, const int* in_sizes, int n_in,
                              void* d_out, int out_size, void* d_ws, size_t ws_size,
                              hipStream_t stream)
{
    const float* cls   = (const float*)d_in[0];
    const float* reg   = (const float*)d_in[1];
    const float* gtb   = (const float*)d_in[2];
    const float* ap    = (const float*)d_in[3];
    const float* st    = (const float*)d_in[4];
    const int*   glab  = (const int*)d_in[5];

    int A = in_sizes[3] / 2;
    int B = in_sizes[0] / (A * C_NUM);
    int G = in_sizes[5] / B;
    int k = A / (G > 1 ? G : 1); if (k > 13) k = 13; if (k < 3) k = 3;

    // ws layout
    unsigned int* mask = (unsigned int*)d_ws;                       // B*A
    float* acc   = (float*)(mask + (size_t)B * A);                  // 3*B
    int*   npos  = (int*)(acc + 3 * B);                             // B
    int*   sel   = npos + B;                                        // B*G*16 (fallback only)
    int*   fgl   = sel + (size_t)B * G * 16;                        // B*FG_STRIDE

    if (A == 8400 && G <= 32) {
        assignraster_kernel<<<B, 1024, 0, stream>>>(gtb, mask, fgl, npos, acc, A, G, k);
    } else {
        assign_kernel<<<B * G, 256, 0, stream>>>(gtb, ap, sel, B, A, G, k);
        raster_kernel<<<B, 256, 0, stream>>>(sel, mask, fgl, npos, acc, A, G, k);
    }

    dim3 g3(128, B);
    cls_kernel<<<g3, 256, 0, stream>>>((const float4*)cls, mask, glab, acc, A, G);

    dim3 g4((FG_STRIDE * 4 + 255) / 256, B);
    boxfg_kernel<<<g4, 256, 0, stream>>>(reg, gtb, ap, st, fgl, npos, acc, A, G);

    final_kernel<<<1, 64, 0, stream>>>(acc, npos, (float*)d_out, B, A);
}

// Round 11
// 153.558 us; speedup vs baseline: 1.0413x; 1.0080x over previous
//
#include <hip/hip_runtime.h>
#include <hip/hip_bf16.h>
#include <cfloat>

#define C_NUM 80
#define CQ 20          // float4 quads per anchor (C_NUM/4)
#define REG_MAXP1 17
#define NS 33          // register slots in fallback assign kernel: covers A <= 8448
#define MAXA 8448      // LDS mask capacity in raster kernels
#define FG_STRIDE 512  // per-image fg-list capacity (>= G*k = 260)
#define FIX_SLOTS (FG_STRIDE * CQ)   // 10240 fixup slots per image
#define FG_BLOCKS 48                 // (FIX_SLOTS + FG_STRIDE*4) / 256

// ---------------- analytic candidate-window helpers (A == 8400 geometry) ----------------
// level0 80x80 @ (ix+0.5)*8 base 0 | level1 40x40 @ (ix+0.5)*16 base 6400 | level2 20x20 @ (ix+0.5)*32 base 8000
__device__ inline void cand_for_slot(int sc, float cx, float cy, float& v, int& idx)
{
    v = FLT_MAX; idx = 0x7fffffff;
    int loc, w, n, strd, base;
    if (sc < 36)      { loc = sc;      w = 6; n = 80; strd = 8;  base = 0; }
    else if (sc < 52) { loc = sc - 36; w = 4; n = 40; strd = 16; base = 6400; }
    else if (sc < 68) { loc = sc - 52; w = 4; n = 20; strd = 32; base = 8000; }
    else return;
    float inv = 1.0f / (float)strd;
    int ix0 = (int)floorf(cx * inv - 0.5f) - (w / 2 - 1);
    int iy0 = (int)floorf(cy * inv - 0.5f) - (w / 2 - 1);
    int ix = ix0 + loc % w, iy = iy0 + loc / w;
    if (ix < 0 || ix >= n || iy < 0 || iy >= n) return;
    float ax = ((float)ix + 0.5f) * (float)strd;
    float ay = ((float)iy + 0.5f) * (float)strd;
    float dx = ax - cx, dy = ay - cy;
    v = dx * dx + dy * dy;
    idx = base + iy * n + ix;
}

// ---------------- K1 (fast): per-image assign (wave per gt) + raster in LDS ----------------
__global__ __launch_bounds__(1024) void assignraster_kernel(const float* __restrict__ gt_boxes,
                              unsigned int* __restrict__ mask,
                              int* __restrict__ fglist,
                              int* __restrict__ npos,
                              float* __restrict__ acc,
                              unsigned int* __restrict__ counter,
                              int A, int G, int k)
{
    __shared__ unsigned int lmask[8400];
    __shared__ int s_cnt;
    int b = blockIdx.x, t = threadIdx.x;
    int wv = t >> 6, lane = t & 63;

    for (int i = t; i < A; i += 1024) lmask[i] = 0u;
    if (t == 0) s_cnt = 0;
    if (t < 3) acc[b * 3 + t] = 0.f;
    if (b == 0 && t == 0) *counter = 0u;
    __syncthreads();

    for (int g = wv; g < G; g += 16) {
        const float* box = gt_boxes + (size_t)(b * G + g) * 4;
        float x0 = box[0], y0 = box[1], x1 = box[2], y1 = box[3];
        float cx = (x0 + x1) * 0.5f, cy = (y0 + y1) * 0.5f;

        float v0, v1; int i0, i1;
        cand_for_slot(lane,      cx, cy, v0, i0);
        cand_for_slot(lane + 64, cx, cy, v1, i1);

        int my_sel = 0x7fffffff;
        for (int it = 0; it < k; ++it) {
            float lb; int li; bool s0;
            if (v0 < v1 || (v0 == v1 && i0 < i1)) { lb = v0; li = i0; s0 = true; }
            else                                   { lb = v1; li = i1; s0 = false; }
            float rb = lb; int ri = li;
            for (int off = 32; off; off >>= 1) {
                float ov = __shfl_down(rb, off);
                int   oi = __shfl_down(ri, off);
                if (ov < rb || (ov == rb && oi < ri)) { rb = ov; ri = oi; }
            }
            int win = __shfl(ri, 0);
            if (lane == it) my_sel = win;
            if (li == win) {
                if (s0) { v0 = FLT_MAX; i0 = 0x7fffffff; }
                else    { v1 = FLT_MAX; i1 = 0x7fffffff; }
            }
        }

        bool inside = false;
        if (lane < k && my_sel < 0x7fffffff) {
            int idx = my_sel, n, strd, base;
            if (idx < 6400)      { n = 80; strd = 8;  base = 0; }
            else if (idx < 8000) { n = 40; strd = 16; base = 6400; }
            else                 { n = 20; strd = 32; base = 8000; }
            int loc = idx - base;
            float ax = ((float)(loc % n) + 0.5f) * (float)strd;
            float ay = ((float)(loc / n) + 0.5f) * (float)strd;
            inside = (ax >= x0) && (ax <= x1) && (ay >= y0) && (ay <= y1);
        }
        unsigned long long ball = __ballot(inside);
        if (lane < k && my_sel < 0x7fffffff) {
            bool asg = ball ? inside : (lane < 3);
            if (asg) atomicOr(&lmask[my_sel], 1u << g);
        }
    }
    __syncthreads();

    for (int i = t; i < A; i += 1024) {
        unsigned int m = lmask[i];
        mask[(size_t)b * A + i] = m;
        bool fg = (m != 0u);
        unsigned long long bal = __ballot(fg);
        int cnt = __popcll(bal);
        int base = 0;
        if (lane == 0 && cnt) base = atomicAdd(&s_cnt, cnt);
        base = __shfl(base, 0);
        if (fg) {
            int pre = __popcll(bal & ((1ull << lane) - 1ull));
            fglist[b * FG_STRIDE + base + pre] = i | ((31 - __clz(m)) << 16);
        }
    }
    __syncthreads();
    if (t == 0) npos[b] = s_cnt;
}

// ---------------- K1 fallback (A != 8400): register-scan top-k -> sel ----------------
__global__ __launch_bounds__(256) void assign_kernel(const float* __restrict__ gt_boxes,
                              const float* __restrict__ anchor_points,
                              int* __restrict__ sel,
                              int B, int A, int G, int k)
{
    __shared__ float s_val[4];
    __shared__ int   s_idx[4];
    __shared__ int   s_sel;
    __shared__ int   s_topk[16];
    __shared__ int   s_anyin;

    int bg = blockIdx.x;
    int b = bg / G, g = bg % G;
    const float* box = gt_boxes + (size_t)(b * G + g) * 4;
    float x0 = box[0], y0 = box[1], x1 = box[2], y1 = box[3];
    float cx = (x0 + x1) * 0.5f, cy = (y0 + y1) * 0.5f;

    int t = threadIdx.x;
    float dv[NS];
#pragma unroll
    for (int s = 0; s < NS; ++s) {
        int i = t + s * 256;
        float d = FLT_MAX;
        if (i < A) {
            float dx = anchor_points[2 * i] - cx;
            float dy = anchor_points[2 * i + 1] - cy;
            d = dx * dx + dy * dy;
        }
        dv[s] = d;
    }

    int wid = t >> 6, lane = t & 63;
    for (int it = 0; it < k; ++it) {
        float best = FLT_MAX; int bi = 0x7fffffff;
#pragma unroll
        for (int s = 0; s < NS; ++s) {
            if (dv[s] < best) { best = dv[s]; bi = t + s * 256; }
        }
        for (int off = 32; off; off >>= 1) {
            float ov = __shfl_down(best, off);
            int   oi = __shfl_down(bi, off);
            if (ov < best || (ov == best && oi < bi)) { best = ov; bi = oi; }
        }
        if (lane == 0) { s_val[wid] = best; s_idx[wid] = bi; }
        __syncthreads();
        if (t == 0) {
            float bv = s_val[0]; int bix = s_idx[0];
#pragma unroll
            for (int w = 1; w < 4; ++w) {
                if (s_val[w] < bv || (s_val[w] == bv && s_idx[w] < bix)) { bv = s_val[w]; bix = s_idx[w]; }
            }
            s_sel = bix;
            s_topk[it] = bix;
        }
        __syncthreads();
        int selx = s_sel;
        if ((selx & 255) == t) {
            int slot = selx >> 8;
#pragma unroll
            for (int s = 0; s < NS; ++s) if (s == slot) dv[s] = FLT_MAX;
        }
    }

    if (t == 0) s_anyin = 0;
    __syncthreads();
    bool inside = false; int aidx = -1;
    if (t < k) {
        aidx = s_topk[t];
        float ax = anchor_points[2 * aidx], ay = anchor_points[2 * aidx + 1];
        inside = (ax >= x0) && (ax <= x1) && (ay >= y0) && (ay <= y1);
        if (inside) atomicOr(&s_anyin, 1);
    }
    __syncthreads();
    if (t < k) {
        bool asg = s_anyin ? inside : (t < 3);
        sel[(size_t)bg * 16 + t] = asg ? aidx : -1;
    }
}

// ---------------- K2 fallback: rasterize per image from sel ----------------
__global__ __launch_bounds__(256) void raster_kernel(const int* __restrict__ sel,
                              unsigned int* __restrict__ mask,
                              int* __restrict__ fglist,
                              int* __restrict__ npos,
                              float* __restrict__ acc,
                              unsigned int* __restrict__ counter,
                              int A, int G, int k)
{
    __shared__ unsigned int lmask[MAXA];
    __shared__ int s_cnt;
    int b = blockIdx.x, t = threadIdx.x;

    for (int i = t; i < A; i += 256) lmask[i] = 0u;
    if (t == 0) s_cnt = 0;
    if (t < 3) acc[b * 3 + t] = 0.f;
    if (b == 0 && t == 0) *counter = 0u;
    __syncthreads();

    for (int i = t; i < G * 16; i += 256) {
        int slot = i & 15;
        if (slot < k) {
            int a = sel[(size_t)(b * G) * 16 + i];
            if (a >= 0) atomicOr(&lmask[a], 1u << (i >> 4));
        }
    }
    __syncthreads();

    for (int i = t; i < A; i += 256) {
        unsigned int m = lmask[i];
        mask[(size_t)b * A + i] = m;
        if (m) {
            int lg = 31 - __clz(m);
            int p = atomicAdd(&s_cnt, 1);
            fglist[b * FG_STRIDE + p] = i | (lg << 16);
        }
    }
    __syncthreads();
    if (t == 0) npos[b] = s_cnt;
}

// ---------------- K3: pure streaming neg-BCE (mask-free, branch-free) ----------------
__global__ __launch_bounds__(256) void cls_stream_kernel(const float4* __restrict__ cls,
                           float* __restrict__ acc, int nq)
{
    int b = blockIdx.y;
    const float4* base = cls + (size_t)b * nq;
    int stride = gridDim.x * 256;
    float neg = 0.f;
    for (int q = blockIdx.x * 256 + threadIdx.x; q < nq; q += stride) {
        float4 v = base[q];
        float p0 = fminf(fmaxf(v.x, 1e-7f), 1.0f - 1e-7f);
        float p1 = fminf(fmaxf(v.y, 1e-7f), 1.0f - 1e-7f);
        float p2 = fminf(fmaxf(v.z, 1e-7f), 1.0f - 1e-7f);
        float p3 = fminf(fmaxf(v.w, 1e-7f), 1.0f - 1e-7f);
        neg -= __logf(1.0f - p0) + __logf(1.0f - p1) + __logf(1.0f - p2) + __logf(1.0f - p3);
    }
    for (int off = 32; off; off >>= 1) neg += __shfl_down(neg, off);
    __shared__ float sn[4];
    int wid = threadIdx.x >> 6, lane = threadIdx.x & 63;
    if (lane == 0) sn[wid] = neg;
    __syncthreads();
    if (threadIdx.x == 0) {
        float N = sn[0] + sn[1] + sn[2] + sn[3];
        atomicAdd(&acc[b * 3 + 1], N);
    }
}

// ---------------- K4: fg fixup (cls correction) + box loss + fused final ----------------
__global__ __launch_bounds__(256) void fgfix_kernel(const float4* __restrict__ cls4,
                           const float* __restrict__ reg,
                           const float* __restrict__ gt_boxes,
                           const float* __restrict__ ap,
                           const float* __restrict__ st,
                           const unsigned int* __restrict__ mask,
                           const int* __restrict__ gt_labels,
                           const int* __restrict__ fglist,
                           const int* __restrict__ npos,
                           float* __restrict__ acc,
                           unsigned int* __restrict__ counter,
                           float* __restrict__ out,
                           int A, int G, int B)
{
    int b = blockIdx.y;
    int idx = blockIdx.x * 256 + threadIdx.x;
    int np = npos[b];
    float posAdd = 0.f, negSub = 0.f, bx = 0.f;

    if (idx < FIX_SLOTS) {
        int e = idx / CQ, cq = idx - e * CQ;
        if (e < np) {
            int ent = fglist[b * FG_STRIDE + e];
            int a = ent & 0xffff;
            unsigned int m = mask[(size_t)b * A + a];
            const int* lab = gt_labels + (size_t)b * G;
            int c0 = cq * 4;
            float4 v = cls4[(size_t)b * A * CQ + (size_t)a * CQ + cq];
            float p0 = fminf(fmaxf(v.x, 1e-7f), 1.0f - 1e-7f);
            float p1 = fminf(fmaxf(v.y, 1e-7f), 1.0f - 1e-7f);
            float p2 = fminf(fmaxf(v.z, 1e-7f), 1.0f - 1e-7f);
            float p3 = fminf(fmaxf(v.w, 1e-7f), 1.0f - 1e-7f);
            unsigned int tm = 0, mm = m;
            while (mm) {
                int g = __ffs(mm) - 1;
                mm &= mm - 1;
                unsigned int d = (unsigned int)(lab[g] - c0);
                if (d < 4u) tm |= 1u << d;
            }
            float n0 = -__logf(1.0f - p0), n1 = -__logf(1.0f - p1);
            float n2 = -__logf(1.0f - p2), n3 = -__logf(1.0f - p3);
            negSub = n0 + n1 + n2 + n3;                 // remove this anchor from neg_all
            posAdd  = (tm & 1u) ? -__logf(p0) : n0;     // target-aware bce into pos
            posAdd += (tm & 2u) ? -__logf(p1) : n1;
            posAdd += (tm & 4u) ? -__logf(p2) : n2;
            posAdd += (tm & 8u) ? -__logf(p3) : n3;
        }
    } else {
        int idx2 = idx - FIX_SLOTS;
        int e = idx2 >> 2, j = idx2 & 3;
        if (e < np) {
            int ent = fglist[b * FG_STRIDE + e];
            int a = ent & 0xffff;
            int lg = ent >> 16;
            float tbj = gt_boxes[(size_t)(b * G + lg) * 4 + j];
            const float* rj = reg + ((size_t)b * A + a) * (4 * REG_MAXP1) + j * REG_MAXP1;
            float rr[REG_MAXP1];
#pragma unroll
            for (int i = 0; i < REG_MAXP1; ++i) rr[i] = rj[i];
            float mx = rr[0];
#pragma unroll
            for (int i = 1; i < REG_MAXP1; ++i) mx = fmaxf(mx, rr[i]);
            float sum = 0.f, dot = 0.f;
#pragma unroll
            for (int i = 0; i < REG_MAXP1; ++i) {
                float ev = __expf(rr[i] - mx);
                sum += ev; dot += ev * (float)i;
            }
            float dist = dot / sum;
            float s = st[a];
            float ac = ap[2 * a + (j & 1)];
            float pbj = (j < 2) ? (ac - dist * s) : (ac + dist * s);
            float df = pbj - tbj;
            float ad = fabsf(df);
            bx = (ad < 1.0f) ? 0.5f * df * df : ad - 0.5f;
        }
    }

    for (int off = 32; off; off >>= 1) {
        posAdd += __shfl_down(posAdd, off);
        negSub += __shfl_down(negSub, off);
        bx     += __shfl_down(bx, off);
    }
    __shared__ float sp[4], sn[4], sb[4];
    __shared__ int s_last;
    int wid = threadIdx.x >> 6, lane = threadIdx.x & 63;
    if (lane == 0) { sp[wid] = posAdd; sn[wid] = negSub; sb[wid] = bx; }
    __syncthreads();
    if (threadIdx.x == 0) {
        float P = sp[0] + sp[1] + sp[2] + sp[3];
        float N = sn[0] + sn[1] + sn[2] + sn[3];
        float X = sb[0] + sb[1] + sb[2] + sb[3];
        if (P != 0.f) atomicAdd(&acc[b * 3 + 0], P);
        if (N != 0.f) atomicAdd(&acc[b * 3 + 1], -N);
        if (X != 0.f) atomicAdd(&acc[b * 3 + 2], X);
        __threadfence();
        unsigned int old = atomicAdd(counter, 1u);
        s_last = (old == (unsigned int)(gridDim.x * gridDim.y) - 1u) ? 1 : 0;
    }
    __syncthreads();

    if (s_last) {
        // final reduction, parallel over images; acc read via device atomics for coherence
        int t = threadIdx.x;
        float cls_c = 0.f, box_c = 0.f;
        if (t < 64) {
            for (int bb = t; bb < B; bb += 64) {
                float a0 = atomicAdd(&acc[bb * 3 + 0], 0.f);
                float a1 = atomicAdd(&acc[bb * 3 + 1], 0.f);
                float a2 = atomicAdd(&acc[bb * 3 + 2], 0.f);
                float npf = (float)npos[bb];
                float neg = a1 / fmaxf(((float)A - npf) * (float)C_NUM, 1.0f);
                float pos = 0.f, box = 0.f;
                if (npf > 0.f) {
                    float pw = fminf((float)A / fmaxf(npf, 1.0f), 50.0f);
                    pos = a0 / fmaxf(npf * (float)C_NUM, 1.0f) * pw;
                    box = a2 / fmaxf(npf * 4.0f, 1.0f);
                }
                cls_c += pos + neg;
                box_c += box;
            }
            for (int off = 32; off; off >>= 1) {
                cls_c += __shfl_down(cls_c, off);
                box_c += __shfl_down(box_c, off);
            }
            if (t == 0) out[0] = cls_c / (float)B * 1.0f + box_c / (float)B * 2.5f;
        }
    }
}

extern "C" void kernel_launch(void* const* d_in, const int* in_sizes, int n_in,
                              void* d_out, int out_size, void* d_ws, size_t ws_size,
                              hipStream_t stream)
{
    const float* cls   = (const float*)d_in[0];
    const float* reg   = (const float*)d_in[1];
    const float* gtb   = (const float*)d_in[2];
    const float* ap    = (const float*)d_in[3];
    const float* st    = (const float*)d_in[4];
    const int*   glab  = (const int*)d_in[5];

    int A = in_sizes[3] / 2;
    int B = in_sizes[0] / (A * C_NUM);
    int G = in_sizes[5] / B;
    int k = A / (G > 1 ? G : 1); if (k > 13) k = 13; if (k < 3) k = 3;

    // ws layout
    unsigned int* mask = (unsigned int*)d_ws;                       // B*A
    float* acc   = (float*)(mask + (size_t)B * A);                  // 3*B
    int*   npos  = (int*)(acc + 3 * B);                             // B
    int*   sel   = npos + B;                                        // B*G*16 (fallback only)
    int*   fgl   = sel + (size_t)B * G * 16;                        // B*FG_STRIDE
    unsigned int* counter = (unsigned int*)(fgl + (size_t)B * FG_STRIDE);  // 1

    if (A == 8400 && G <= 32) {
        assignraster_kernel<<<B, 1024, 0, stream>>>(gtb, mask, fgl, npos, acc, counter, A, G, k);
    } else {
        assign_kernel<<<B * G, 256, 0, stream>>>(gtb, ap, sel, B, A, G, k);
        raster_kernel<<<B, 256, 0, stream>>>(sel, mask, fgl, npos, acc, counter, A, G, k);
    }

    dim3 g3(128, B);
    cls_stream_kernel<<<g3, 256, 0, stream>>>((const float4*)cls, acc, A * CQ);

    dim3 g4(FG_BLOCKS, B);
    fgfix_kernel<<<g4, 256, 0, stream>>>((const float4*)cls, reg, gtb, ap, st,
                                         mask, glab, fgl, npos, acc, counter,
                                         (float*)d_out, A, G, B);
}